// Round 1
// baseline (869.539 us; speedup 1.0000x reference)
//
#include <hip/hip_runtime.h>

// ---------------------------------------------------------------------------
// ContrastiveLoss (SCAN t2i cross-attention) on MI355X.
// Shapes: N=256 images x 256 captions, R=36 regions, L=50 words, D=256.
//
// Math restructuring:
//   G[r,l]   = <im_i[r], s_j[l]>                       (bf16 MFMA, f32 accum)
//   A[r,l]   = leaky(G)*mask / (||leaky(G)*mask||_l + eps)
//   a[r,l]   = softmax_r(9*A)
//   num[l]   = sum_r a[r,l]*G[r,l]
//   wn2[l]   = a(:,l)^T Gram_i a(:,l),  Gram_i = im_i im_i^T  (f32, precomp)
//   sim[l]   = num / max(sqrt(wn2)*||s_j[l]||, eps)
//   score    = LSE_{l<len}(6*sim)/6
// Loss: sum of two hinge terms vs diagonal.
// ---------------------------------------------------------------------------

typedef unsigned short u16;
typedef unsigned int u32;

typedef __attribute__((ext_vector_type(8))) __bf16 bf16x8;
typedef __attribute__((ext_vector_type(4))) float floatx4;

#define NN 256
#define RR 36
#define LL 50
#define DD 256
#define GSTR 53

__device__ __forceinline__ u16 f2bf(float v) {
  u32 u = __builtin_bit_cast(u32, v);
  u += 0x7fffu + ((u >> 16) & 1u);   // round-to-nearest-even (no NaN inputs)
  return (u16)(u >> 16);
}

// ---- prep: im -> bf16, Gram_i = im_i im_i^T -------------------------------
__global__ void prep_im_kernel(const float* __restrict__ im,
                               u16* __restrict__ im_bf,
                               float* __restrict__ gram) {
  const int i = blockIdx.x;
  const int t = threadIdx.x;
  __shared__ float L[RR * 260];
  const float* src = im + (size_t)i * (RR * DD);
  for (int e = t; e < RR * DD; e += 256) {
    int r = e >> 8, d = e & 255;
    float v = src[e];
    L[r * 260 + d] = v;
    im_bf[(size_t)i * (RR * DD) + e] = f2bf(v);
  }
  __syncthreads();
  float* gout = gram + (size_t)i * (RR * RR);
  for (int e = t; e < RR * RR; e += 256) {
    int r1 = e / RR, r2 = e - r1 * RR;
    const float* pa = &L[r1 * 260];
    const float* pb = &L[r2 * 260];
    float acc = 0.f;
    #pragma unroll 4
    for (int d = 0; d < DD; d += 4) {
      float4 va = *(const float4*)(pa + d);
      float4 vb = *(const float4*)(pb + d);
      acc += va.x * vb.x + va.y * vb.y + va.z * vb.z + va.w * vb.w;
    }
    gout[e] = acc;
  }
}

// ---- prep: s -> bf16, cn[j,l] = ||s_j[l]|| --------------------------------
__global__ void prep_s_kernel(const float* __restrict__ s,
                              u16* __restrict__ s_bf,
                              float* __restrict__ cn) {
  const int j = blockIdx.x;
  const int t = threadIdx.x;
  const float* src = s + (size_t)j * (LL * DD);
  for (int e = t; e < LL * DD; e += 256)
    s_bf[(size_t)j * (LL * DD) + e] = f2bf(src[e]);
  const int l = t >> 2, q = t & 3;
  float acc = 0.f;
  if (l < LL) {
    const float* row = src + l * DD + q * 64;
    #pragma unroll 4
    for (int d = 0; d < 64; ++d) { float v = row[d]; acc = fmaf(v, v, acc); }
  }
  acc += __shfl_xor(acc, 1);
  acc += __shfl_xor(acc, 2);
  if (l < LL && q == 0) cn[j * LL + l] = sqrtf(acc);
}

// ---- main: one wave per (image i, caption j) pair -------------------------
__global__ __launch_bounds__(64) void xattn_kernel(
    const u16* __restrict__ im_bf, const u16* __restrict__ s_bf,
    const float* __restrict__ gram, const float* __restrict__ cn,
    const int* __restrict__ cap, float* __restrict__ scores) {
  const int bid = blockIdx.x;
  const int i = bid >> 8;
  const int j = bid & 255;
  const int lane = threadIdx.x;
  const int lo = lane & 15;
  const int hi = lane >> 4;

  __shared__ float Gs[RR * GSTR + 32];
  __shared__ float rinv9[RR];   // 9 / (rownorm + eps)

  const int len = cap[j];

  // ---- Phase A: G = im_i @ s_j^T via bf16 MFMA (M=48 pad, N=64 pad, K=256)
  floatx4 acc[3][4];
  #pragma unroll
  for (int m = 0; m < 3; ++m)
    #pragma unroll
    for (int n = 0; n < 4; ++n)
      acc[m][n] = floatx4{0.f, 0.f, 0.f, 0.f};

  const u16* imp = im_bf + (size_t)i * (RR * DD);
  const u16* sp  = s_bf  + (size_t)j * (LL * DD);
  const uint4 zu = {0u, 0u, 0u, 0u};

  #pragma unroll 2
  for (int kt = 0; kt < 8; ++kt) {
    const int k0 = kt * 32 + hi * 8;
    bf16x8 af[3], bfr[4];
    #pragma unroll
    for (int m = 0; m < 3; ++m) {
      int r = m * 16 + lo;
      uint4 v = (r < RR) ? *reinterpret_cast<const uint4*>(imp + r * DD + k0) : zu;
      af[m] = __builtin_bit_cast(bf16x8, v);
    }
    #pragma unroll
    for (int n = 0; n < 4; ++n) {
      int l = n * 16 + lo;
      uint4 v = (l < LL) ? *reinterpret_cast<const uint4*>(sp + l * DD + k0) : zu;
      bfr[n] = __builtin_bit_cast(bf16x8, v);
    }
    #pragma unroll
    for (int m = 0; m < 3; ++m)
      #pragma unroll
      for (int n = 0; n < 4; ++n)
        acc[m][n] = __builtin_amdgcn_mfma_f32_16x16x32_bf16(af[m], bfr[n], acc[m][n], 0, 0, 0);
  }

  // write G to LDS: D-frag layout col=lane&15 (=l), row=(lane>>4)*4+q (=r)
  #pragma unroll
  for (int m = 0; m < 3; ++m) {
    int r0 = m * 16 + hi * 4;
    #pragma unroll
    for (int n = 0; n < 4; ++n) {
      int l = n * 16 + lo;
      if (l < LL) {
        #pragma unroll
        for (int q = 0; q < 4; ++q) {
          int r = r0 + q;
          if (r < RR) Gs[r * GSTR + l] = acc[m][n][q];
        }
      }
    }
  }
  __syncthreads();

  // ---- C1: per-region l2 norm over valid words (mask applied pre-norm)
  if (lane < RR) {
    float ss = 0.f;
    for (int l = 0; l < len; ++l) {
      float g = Gs[lane * GSTR + l];
      float v = (g > 0.f) ? g : 0.1f * g;
      ss = fmaf(v, v, ss);
    }
    rinv9[lane] = 9.f / (sqrtf(ss) + 1e-8f);
  }
  __syncthreads();

  // ---- C2: per-word column math (lane <-> word l)
  const int l = (lane < LL - 1) ? lane : (LL - 1);
  const bool valid = (lane < len);

  float x[RR];
  float mx = -1e30f;
  #pragma unroll
  for (int r = 0; r < RR; ++r) {
    float g = Gs[r * GSTR + l];
    float v = (g > 0.f) ? g : 0.1f * g;
    v = v * rinv9[r];
    x[r] = v;
    mx = fmaxf(mx, v);
  }
  float psum = 0.f;
  #pragma unroll
  for (int r = 0; r < RR; ++r) {
    float p = __expf(x[r] - mx);
    x[r] = p;             // unnormalized softmax weights
    psum += p;
  }
  const float inv = 1.f / psum;

  const float* gm = gram + (size_t)i * (RR * RR);  // wave-uniform -> s_load
  float num = 0.f, wn2 = 0.f;
  #pragma unroll
  for (int r = 0; r < RR; ++r) {
    float t = 0.f;
    #pragma unroll
    for (int rp = 0; rp < RR; ++rp)
      t = fmaf(gm[r * RR + rp], x[rp], t);
    wn2 = fmaf(x[r], t, wn2);
    num = fmaf(x[r], Gs[r * GSTR + l], num);
  }
  num *= inv;
  wn2 *= inv * inv;

  const float cnl = cn[j * LL + l];
  const float sim = num / fmaxf(sqrtf(wn2) * cnl, 1e-8f);
  float z = valid ? 6.f * sim : -__builtin_inff();

  // LSE across the wave (invalid lanes contribute exp(-inf)=0)
  float mz = z;
  #pragma unroll
  for (int o = 32; o; o >>= 1) mz = fmaxf(mz, __shfl_xor(mz, o));
  float e = __expf(z - mz);
  #pragma unroll
  for (int o = 32; o; o >>= 1) e += __shfl_xor(e, o);
  if (lane == 0) scores[i * NN + j] = (mz + __logf(e)) / 6.f;
}

// ---- loss: hinge terms vs diagonal, full reduction ------------------------
__global__ void loss_kernel(const float* __restrict__ sc, float* __restrict__ out) {
  __shared__ float diag[NN];
  __shared__ float wsum[4];
  const int t = threadIdx.x;
  diag[t] = sc[t * NN + t];
  __syncthreads();
  const float di = diag[t];
  float acc = 0.f;
  for (int jj = 0; jj < NN; ++jj) {
    if (jj == t) continue;
    float v = sc[t * NN + jj];
    acc += fmaxf(0.2f + v - di, 0.f) + fmaxf(0.2f + v - diag[jj], 0.f);
  }
  #pragma unroll
  for (int o = 32; o; o >>= 1) acc += __shfl_xor(acc, o);
  if ((t & 63) == 0) wsum[t >> 6] = acc;
  __syncthreads();
  if (t == 0) out[0] = wsum[0] + wsum[1] + wsum[2] + wsum[3];
}

// ---------------------------------------------------------------------------
extern "C" void kernel_launch(void* const* d_in, const int* in_sizes, int n_in,
                              void* d_out, int out_size, void* d_ws, size_t ws_size,
                              hipStream_t stream) {
  const float* im = (const float*)d_in[0];
  const float* s  = (const float*)d_in[1];
  const int* cap  = (const int*)d_in[2];
  float* out = (float*)d_out;

  char* ws = (char*)d_ws;
  u16*   im_bf  = (u16*)(ws);                                  // 4,718,592 B
  u16*   s_bf   = (u16*)(ws + 4718592);                        // 6,553,600 B
  float* gram   = (float*)(ws + 4718592 + 6553600);            // 1,327,104 B
  float* cn     = (float*)(ws + 4718592 + 6553600 + 1327104);  //    51,200 B
  float* scores = (float*)(ws + 4718592 + 6553600 + 1327104 + 51200); // 262,144 B

  prep_im_kernel<<<dim3(NN), dim3(256), 0, stream>>>(im, im_bf, gram);
  prep_s_kernel<<<dim3(NN), dim3(256), 0, stream>>>(s, s_bf, cn);
  xattn_kernel<<<dim3(NN * NN), dim3(64), 0, stream>>>(im_bf, s_bf, gram, cn, cap, scores);
  loss_kernel<<<dim3(1), dim3(256), 0, stream>>>(scores, out);
}

// Round 3
// 546.460 us; speedup vs baseline: 1.5912x; 1.5912x over previous
//
#include <hip/hip_runtime.h>

// ---------------------------------------------------------------------------
// ContrastiveLoss (SCAN t2i cross-attention) on MI355X — round 2 (resubmit).
// N=256x256 pairs, R=36 regions, L=50 words, D=256.
//
//   G[r,l] = <im_i[r], s_j[l]>                  (bf16 MFMA, f32 accum)
//   rinv[r]= 9*log2e / (||leaky(G[r,:len])|| + eps)
//   p[r,l] = exp2(leaky(G)*rinv - max_r)        (unnormalized softmax wts)
//   num[l] = sum_r p*G        (inline in softmax lane)
//   t      = Gram_i @ p       (bf16 MFMA, Gram = im im^T precomputed)
//   wn2[l] = sum_r p*t        (fragment elementwise + shfl reduce)
//   sim    = (num/ps) / max(sqrt(wn2)/ps * cn, eps);  score = LSE(6 sim)/6
// ---------------------------------------------------------------------------

typedef unsigned short u16;
typedef unsigned int u32;

typedef __attribute__((ext_vector_type(8))) __bf16 bf16x8;
typedef __attribute__((ext_vector_type(4))) float floatx4;

#define NN 256
#define RR 36
#define LL 50
#define DD 256
#define RP 48   // padded region dim
#define LP 64   // padded word dim
#define KP 64   // padded K for gram matvec
#define ASTR 68 // bf16 stride of per-wave LDS rows (136B = 4-way max alias)

__device__ __forceinline__ u16 f2bf(float v) {
  u32 u = __builtin_bit_cast(u32, v);
  u += 0x7fffu + ((u >> 16) & 1u);   // RNE (inputs never NaN)
  return (u16)(u >> 16);
}
__device__ __forceinline__ float bflo(u32 w) { return __builtin_bit_cast(float, w << 16); }
__device__ __forceinline__ float bfhi(u32 w) { return __builtin_bit_cast(float, w & 0xffff0000u); }

// ---- prep: im -> bf16 padded [48][256], Gram_i -> bf16 padded [48][64] ----
__global__ void prep_im_kernel(const float* __restrict__ im,
                               u16* __restrict__ im_bf,
                               u16* __restrict__ gram_bf) {
  const int i = blockIdx.x;
  const int t = threadIdx.x;
  __shared__ float L[RR * 260];
  const float* src = im + (size_t)i * (RR * DD);
  u16* dst = im_bf + (size_t)i * (RP * DD);
  for (int e = t; e < RR * DD; e += 256) {
    int r = e >> 8, d = e & 255;
    float v = src[e];
    L[r * 260 + d] = v;
    dst[e] = f2bf(v);
  }
  for (int e = RR * DD + t; e < RP * DD; e += 256) dst[e] = 0;
  __syncthreads();
  u16* g = gram_bf + (size_t)i * (RP * KP);
  for (int e = t; e < RP * KP; e += 256) {
    int r1 = e >> 6, r2 = e & 63;
    if (r1 < RR && r2 < RR) {
      const float* pa = &L[r1 * 260];
      const float* pb = &L[r2 * 260];
      float acc = 0.f;
      #pragma unroll 4
      for (int d = 0; d < DD; d += 4) {
        float4 va = *(const float4*)(pa + d);
        float4 vb = *(const float4*)(pb + d);
        acc += va.x * vb.x + va.y * vb.y + va.z * vb.z + va.w * vb.w;
      }
      g[e] = f2bf(acc);
    } else {
      g[e] = 0;
    }
  }
}

// ---- prep: s -> bf16 padded [64][256], cn[j,l] = ||s_j[l]|| ---------------
__global__ void prep_s_kernel(const float* __restrict__ s,
                              u16* __restrict__ s_bf,
                              float* __restrict__ cn) {
  const int j = blockIdx.x;
  const int t = threadIdx.x;
  const float* src = s + (size_t)j * (LL * DD);
  u16* dst = s_bf + (size_t)j * (LP * DD);
  for (int e = t; e < LL * DD; e += 256) dst[e] = f2bf(src[e]);
  for (int e = LL * DD + t; e < LP * DD; e += 256) dst[e] = 0;
  const int l = t >> 2, q = t & 3;
  float acc = 0.f;
  if (l < LL) {
    const float* row = src + l * DD + q * 64;
    #pragma unroll 4
    for (int d = 0; d < 64; ++d) { float v = row[d]; acc = fmaf(v, v, acc); }
  }
  acc += __shfl_xor(acc, 1);
  acc += __shfl_xor(acc, 2);
  if (l < LL && q == 0) cn[j * LL + l] = sqrtf(acc);
}

// ---- main: 4 waves/block, one (i,j) pair per wave -------------------------
__global__ __launch_bounds__(256, 4) void xattn_kernel(
    const u16* __restrict__ im_bf, const u16* __restrict__ s_bf,
    const u16* __restrict__ gram_bf, const float* __restrict__ cn,
    const int* __restrict__ cap, float* __restrict__ scores) {
  __shared__ u16 buf[4][LP * ASTR];   // per-wave: G^T (bf16) then a^T in place
  __shared__ float nps[4][LP][2];     // per-word {num, psum}

  const int wid  = threadIdx.x >> 6;
  const int lane = threadIdx.x & 63;
  const int lo = lane & 15, hi = lane >> 4;
  const int i = blockIdx.x >> 6;
  const int j = ((blockIdx.x & 63) << 2) | wid;
  const int len = cap[j];
  const int nv = (len > 48) ? 4 : 3;  // wave-uniform n-tile count

  u16* mybuf = buf[wid];

  // zero my buffer once (K-pad cols 36..67 and maybe-unwritten rows must be 0)
  {
    uint4 z4 = {0u, 0u, 0u, 0u};
    uint4* zp = (uint4*)mybuf;
    #pragma unroll
    for (int k = 0; k < 8; ++k) zp[lane + (k << 6)] = z4;
    if (lane < 32) zp[512 + lane] = z4;
  }

  // ---- Phase A: G = im_i @ s_j^T (M=48, N=16*nv, K=256) -------------------
  floatx4 acc[3][4];
  #pragma unroll
  for (int m = 0; m < 3; ++m)
    #pragma unroll
    for (int n = 0; n < 4; ++n) acc[m][n] = floatx4{0.f, 0.f, 0.f, 0.f};

  const u16* imp = im_bf + (size_t)i * (RP * DD);
  const u16* sp  = s_bf  + (size_t)j * (LP * DD);

  #pragma unroll 2
  for (int kt = 0; kt < 8; ++kt) {
    const int k0 = (kt << 5) + (hi << 3);
    bf16x8 af[3], bfr[4];
    #pragma unroll
    for (int m = 0; m < 3; ++m)
      af[m] = __builtin_bit_cast(bf16x8, *(const uint4*)(imp + (m * 16 + lo) * DD + k0));
    #pragma unroll
    for (int n = 0; n < 4; ++n)
      if (n < nv)
        bfr[n] = __builtin_bit_cast(bf16x8, *(const uint4*)(sp + (n * 16 + lo) * DD + k0));
    #pragma unroll
    for (int m = 0; m < 3; ++m)
      #pragma unroll
      for (int n = 0; n < 4; ++n)
        if (n < nv)
          acc[m][n] = __builtin_amdgcn_mfma_f32_16x16x32_bf16(af[m], bfr[n], acc[m][n], 0, 0, 0);
  }

  // Gram A-fragments (global, wave-uniform row block -> L1-hot)
  bf16x8 gA[3][2];
  const u16* gp = gram_bf + (size_t)i * (RP * KP);
  #pragma unroll
  for (int m = 0; m < 3; ++m)
    #pragma unroll
    for (int kt = 0; kt < 2; ++kt)
      gA[m][kt] = __builtin_bit_cast(bf16x8,
          *(const uint4*)(gp + (m * 16 + lo) * KP + (kt << 5) + (hi << 3)));

  // write G^T to LDS bf16: buf[l][r]  (D-frag: row r=16m+4hi+q, col l=16n+lo)
  #pragma unroll
  for (int n = 0; n < 4; ++n) {
    if (n < nv) {
      #pragma unroll
      for (int m = 0; m < 3; ++m) {
        u32 w0 = (u32)f2bf(acc[m][n][0]) | ((u32)f2bf(acc[m][n][1]) << 16);
        u32 w1 = (u32)f2bf(acc[m][n][2]) | ((u32)f2bf(acc[m][n][3]) << 16);
        uint2 t; t.x = w0; t.y = w1;
        *(uint2*)&mybuf[(n * 16 + lo) * ASTR + m * 16 + hi * 4] = t;
      }
    }
  }
  __syncthreads();

  // ---- C1: per-region row norms over valid words --------------------------
  float rinv = 0.f;
  if (lane < RR) {
    float ss = 0.f;
    for (int l = 0; l < len; ++l) {
      float g = bflo((u32)mybuf[l * ASTR + lane]);
      float v = fmaxf(g, 0.1f * g);
      ss = fmaf(v, v, ss);
    }
    rinv = 12.984255368000671f / (sqrtf(ss) + 1e-8f);  // 9*log2e/(norm+eps)
  }
  // broadcast per-region scales into SGPRs
  float sr[RR];
  #pragma unroll
  for (int r = 0; r < RR; ++r)
    sr[r] = __builtin_bit_cast(float,
        __builtin_amdgcn_readlane(__builtin_bit_cast(int, rinv), r));

  // ---- C2: per-word softmax (lane = word l), num inline, a^T in place -----
  u32 rw[18];
  {
    const uint2* rp = (const uint2*)&mybuf[lane * ASTR];
    #pragma unroll
    for (int k = 0; k < 9; ++k) { uint2 t = rp[k]; rw[2 * k] = t.x; rw[2 * k + 1] = t.y; }
  }
  float mx = -1e30f;
  #pragma unroll
  for (int r = 0; r < RR; ++r) {
    u32 w = rw[r >> 1];
    float g = (r & 1) ? bfhi(w) : bflo(w);
    float v = fmaxf(g, 0.1f * g) * sr[r];
    mx = fmaxf(mx, v);
  }
  float psum = 0.f, num = 0.f, pe = 0.f;
  u32 pk[18];
  #pragma unroll
  for (int r = 0; r < RR; ++r) {
    u32 w = rw[r >> 1];
    float g = (r & 1) ? bfhi(w) : bflo(w);
    float v = fmaxf(g, 0.1f * g) * sr[r];
    float p = exp2f(v - mx);
    psum += p;
    num = fmaf(p, g, num);
    if (r & 1) pk[r >> 1] = (u32)f2bf(pe) | ((u32)f2bf(p) << 16);
    else pe = p;
  }
  {
    uint2* wp = (uint2*)&mybuf[lane * ASTR];
    #pragma unroll
    for (int k = 0; k < 9; ++k) { uint2 t; t.x = pk[2 * k]; t.y = pk[2 * k + 1]; wp[k] = t; }
    nps[wid][lane][0] = num;
    nps[wid][lane][1] = psum;
  }
  __syncthreads();

  // ---- matvec: t = Gram_i @ a  (M=48, N=16*nv, K=64 zero-padded) ----------
  floatx4 tac[3][4];
  #pragma unroll
  for (int m = 0; m < 3; ++m)
    #pragma unroll
    for (int n = 0; n < 4; ++n) tac[m][n] = floatx4{0.f, 0.f, 0.f, 0.f};

  #pragma unroll
  for (int kt = 0; kt < 2; ++kt) {
    bf16x8 gB[4];
    #pragma unroll
    for (int n = 0; n < 4; ++n) {
      if (n < nv) {
        const uint2* bp = (const uint2*)&mybuf[(n * 16 + lo) * ASTR + (kt << 5) + (hi << 3)];
        uint2 b0 = bp[0], b1 = bp[1];
        uint4 bb; bb.x = b0.x; bb.y = b0.y; bb.z = b1.x; bb.w = b1.y;
        gB[n] = __builtin_bit_cast(bf16x8, bb);
      }
    }
    #pragma unroll
    for (int m = 0; m < 3; ++m)
      #pragma unroll
      for (int n = 0; n < 4; ++n)
        if (n < nv)
          tac[m][n] = __builtin_amdgcn_mfma_f32_16x16x32_bf16(gA[m][kt], gB[n], tac[m][n], 0, 0, 0);
  }

  // ---- wn2 = sum_r a*t per column (fragment elementwise + hi-group reduce)
  float wn2p[4];
  #pragma unroll
  for (int n = 0; n < 4; ++n) {
    wn2p[n] = 0.f;
    if (n < nv) {
      float w = 0.f;
      #pragma unroll
      for (int m = 0; m < 3; ++m) {
        uint2 av = *(const uint2*)&mybuf[(n * 16 + lo) * ASTR + m * 16 + hi * 4];
        w = fmaf(bflo(av.x), tac[m][n][0], w);
        w = fmaf(bfhi(av.x), tac[m][n][1], w);
        w = fmaf(bflo(av.y), tac[m][n][2], w);
        w = fmaf(bfhi(av.y), tac[m][n][3], w);
      }
      w += __shfl_xor(w, 16);
      w += __shfl_xor(w, 32);
      wn2p[n] = w;   // all 4 hi-duplicates now hold full sum over r
    }
  }

  // ---- finalize per column + wave LSE (4x duplicate -> log2 S - 2) --------
  float m4 = -1e30f, zz[4];
  bool vld[4];
  #pragma unroll
  for (int n = 0; n < 4; ++n) { zz[n] = -1e30f; vld[n] = false; }
  #pragma unroll
  for (int n = 0; n < 4; ++n) {
    if (n < nv) {
      const int col = n * 16 + lo;
      float numv = nps[wid][col][0];
      float ps   = nps[wid][col][1];
      float inv  = __builtin_amdgcn_rcpf(ps);
      float wn2  = fmaxf(wn2p[n] * inv * inv, 0.f);
      float nm   = numv * inv;
      float cnl  = (col < LL) ? cn[j * LL + col] : 1.f;
      float den  = fmaxf(sqrtf(wn2) * cnl, 1e-8f);
      float sim  = nm * __builtin_amdgcn_rcpf(den);
      zz[n] = sim * 8.656170245333781f;     // 6*log2e
      vld[n] = (col < len);
      if (vld[n]) m4 = fmaxf(m4, zz[n]);
    }
  }
  #pragma unroll
  for (int off = 1; off < 64; off <<= 1) m4 = fmaxf(m4, __shfl_xor(m4, off));
  float e4 = 0.f;
  #pragma unroll
  for (int n = 0; n < 4; ++n)
    if (n < nv) e4 += vld[n] ? exp2f(zz[n] - m4) : 0.f;
  #pragma unroll
  for (int off = 1; off < 64; off <<= 1) e4 += __shfl_xor(e4, off);
  if (lane == 0)
    scores[i * NN + j] = (m4 + log2f(e4) - 2.0f) * 0.11552453009332421f; // ln2/6
}

// ---- loss: hinge terms vs diagonal, full reduction ------------------------
__global__ void loss_kernel(const float* __restrict__ sc, float* __restrict__ out) {
  __shared__ float diag[NN];
  __shared__ float wsum[4];
  const int t = threadIdx.x;
  diag[t] = sc[t * NN + t];
  __syncthreads();
  const float di = diag[t];
  float acc = 0.f;
  for (int jj = 0; jj < NN; ++jj) {
    if (jj == t) continue;
    float v = sc[t * NN + jj];
    acc += fmaxf(0.2f + v - di, 0.f) + fmaxf(0.2f + v - diag[jj], 0.f);
  }
  #pragma unroll
  for (int o = 32; o; o >>= 1) acc += __shfl_xor(acc, o);
  if ((t & 63) == 0) wsum[t >> 6] = acc;
  __syncthreads();
  if (t == 0) out[0] = wsum[0] + wsum[1] + wsum[2] + wsum[3];
}

// ---------------------------------------------------------------------------
extern "C" void kernel_launch(void* const* d_in, const int* in_sizes, int n_in,
                              void* d_out, int out_size, void* d_ws, size_t ws_size,
                              hipStream_t stream) {
  const float* im = (const float*)d_in[0];
  const float* s  = (const float*)d_in[1];
  const int* cap  = (const int*)d_in[2];
  float* out = (float*)d_out;

  char* ws = (char*)d_ws;
  u16*   im_bf   = (u16*)(ws);                         //  6,291,456 B
  u16*   s_bf    = (u16*)(ws + 6291456);               //  8,388,608 B
  u16*   gram_bf = (u16*)(ws + 14680064);              //  1,572,864 B
  float* cn      = (float*)(ws + 16252928);            //     51,200 B
  float* scores  = (float*)(ws + 16304128);            //    262,144 B

  prep_im_kernel<<<dim3(NN), dim3(256), 0, stream>>>(im, im_bf, gram_bf);
  prep_s_kernel<<<dim3(NN), dim3(256), 0, stream>>>(s, s_bf, cn);
  xattn_kernel<<<dim3(NN * 64), dim3(256), 0, stream>>>(im_bf, s_bf, gram_bf, cn, cap, scores);
  loss_kernel<<<dim3(1), dim3(256), 0, stream>>>(scores, out);
}